// Round 14
// baseline (149.421 us; speedup 1.0000x reference)
//
#include <hip/hip_runtime.h>
#include <cmath>

#define NBATCH 8
#define NCH    256
#define NH     80
#define NW     160
#define NDISP  24
#define FAC    8

constexpr int TPB1  = 320;                 // 5 waves: 8 cg x 40 wq (full 160-w row)
constexpr int LPAD  = 164;                 // L row stride (floats), 164%32=4 -> conflict-free reads
constexpr int RPAD  = 188;                 // 24 apron + 160 payload + 4 pad; 188%32=28
constexpr int ROFF  = 8 * LPAD;            // 1312
constexpr int BUFSZ = ROFF + 8 * RPAD;     // 2816 floats per buffer (11264 B), 2 buffers

typedef float f4v __attribute__((ext_vector_type(4)));   // native vector for nontemporal builtins

// Barrier WITHOUT vmcnt drain: LDS visibility only. Staged global loads (VGPR-destined)
// stay in flight across it; the compiler inserts counted vmcnt waits at the ds_write.
#define BARSYNC() asm volatile("s_waitcnt lgkmcnt(0)\n\ts_barrier" ::: "memory")

__device__ __forceinline__ float f4c(const float4& v, int k) {
  switch (k) { case 0: return v.x; case 1: return v.y; case 2: return v.z; default: return v.w; }
}

// ---------------- K1: full-row cost volume + top3 + softmax expectation ----------------
// block = one (b,h) row; thread = (cg = t&7, wq = t>>3 in [0,40)); 96 accumulators.
// Staging: per 8-ch slab, each thread 1 float4 of L + 1 of R — 40-thread contiguous 640-B
// channel-row segments (K2's proven access shape; no scattered 1.6MB-stride segments, and
// R fetched exactly once: 210 MB total). ds_write to PADDED rows; persistent zero aprons.
__global__ __launch_bounds__(TPB1) void cost_topk_kernel(
    const float* __restrict__ left, const float* __restrict__ right,
    float* __restrict__ disp)
{
  __shared__ float smem[2 * BUFSZ];        // 22528 B

  const int t   = threadIdx.x;
  const int cg  = t & 7;
  const int wq  = t >> 3;                  // 0..39
  const int w0  = wq * 4;
  const int row = blockIdx.x;              // b*NH + h
  const int b   = row / NH;
  const int h   = row % NH;

  const size_t hw = (size_t)NH * NW;

  // persistent R aprons (x<0 -> 0): rows' first 24 floats, both buffers, written once
  for (int q = t; q < 2 * 8 * 24; q += TPB1) {
    int bu = q / 192, r = q % 192, ch = r / 24, k = r % 24;
    smem[bu * BUFSZ + ROFF + ch * RPAD + k] = 0.f;
  }

  // staging map: thread t covers channel (slab*8 + cht), floats [fl*4, fl*4+3] of the row
  const int cht = t / 40, fl = t % 40;
  const float* srcL = left  + ((size_t)b * NCH + cht) * hw + (size_t)h * NW + fl * 4;
  const float* srcR = right + ((size_t)b * NCH + cht) * hw + (size_t)h * NW + fl * 4;
  const size_t sstep = 8 * hw;

  float* const wl0 = &smem[0 * BUFSZ + cht * LPAD + fl * 4];
  float* const wr0 = &smem[0 * BUFSZ + ROFF + cht * RPAD + 24 + fl * 4];
  float* const wl1 = wl0 + BUFSZ;
  float* const wr1 = wr0 + BUFSZ;

  // compute-side row bases (this thread's channel = slab*8 + cg)
  const float* const Lb0 = &smem[0 * BUFSZ + cg * LPAD + w0];
  const float* const Rb0 = &smem[0 * BUFSZ + ROFF + cg * RPAD + w0];  // = R[w0-24]
  const float* const Lb1 = Lb0 + BUFSZ;
  const float* const Rb1 = Rb0 + BUFSZ;

  float acc[NDISP][4];
#pragma unroll
  for (int i = 0; i < NDISP; ++i)
#pragma unroll
    for (int ws = 0; ws < 4; ++ws) acc[i][ws] = 0.f;

  auto fmastep = [&](const float* Lp, const float* Rp) {
    float4 Lq = *reinterpret_cast<const float4*>(Lp);
    float4 Qa = *reinterpret_cast<const float4*>(Rp);
#pragma unroll
    for (int g = 0; g < 6; ++g) {
      float4 Qb = *reinterpret_cast<const float4*>(Rp + 4 * (g + 1));
      const int i0 = 20 - 4 * g;
#pragma unroll
      for (int di = 0; di < 4; ++di)
#pragma unroll
        for (int ws = 0; ws < 4; ++ws) {
          const int pos = ws - di + 4;               // 1..7 in [Qa|Qb]
          float rv = (pos < 4) ? f4c(Qa, pos) : f4c(Qb, pos - 4);
          acc[i0 + di][ws] = __builtin_fmaf(f4c(Lq, ws), rv, acc[i0 + di][ws]);
        }
      Qa = Qb;
    }
  };

  // prologue: load slabs 0,1 into named sets A,B; write buf0 <- A (counted vmcnt)
  float4 Al, Ar, Bl, Br;
  Al = *reinterpret_cast<const float4*>(srcL);
  Ar = *reinterpret_cast<const float4*>(srcR);
  srcL += sstep; srcR += sstep;
  Bl = *reinterpret_cast<const float4*>(srcL);
  Br = *reinterpret_cast<const float4*>(srcR);
  srcL += sstep; srcR += sstep;
  *reinterpret_cast<float4*>(wl0) = Al;
  *reinterpret_cast<float4*>(wr0) = Ar;
  BARSYNC();                                   // buf0 (slab 0) + aprons visible

  // steady state: even step {load A<-slab j+2; write buf1<-B(j+1); compute buf0(j)};
  //               odd step  {load B<-slab j+3; write buf0<-A(j+2); compute buf1(j+1)}
#pragma unroll 1
  for (int jj = 0; jj < 32; jj += 2) {
    if (jj + 2 < 32) {
      Al = *reinterpret_cast<const float4*>(srcL);
      Ar = *reinterpret_cast<const float4*>(srcR);
      srcL += sstep; srcR += sstep;
    }
    __builtin_amdgcn_sched_barrier(0);         // pin load issue before writes/compute
    *reinterpret_cast<float4*>(wl1) = Bl;      // slab jj+1 (jj<=30 -> always valid)
    *reinterpret_cast<float4*>(wr1) = Br;
    fmastep(Lb0, Rb0);                         // slab jj
    BARSYNC();

    if (jj + 3 < 32) {
      Bl = *reinterpret_cast<const float4*>(srcL);
      Br = *reinterpret_cast<const float4*>(srcR);
      srcL += sstep; srcR += sstep;
    }
    __builtin_amdgcn_sched_barrier(0);
    if (jj + 2 < 32) {
      *reinterpret_cast<float4*>(wl0) = Al;    // slab jj+2
      *reinterpret_cast<float4*>(wr0) = Ar;
    }
    fmastep(Lb1, Rb1);                         // slab jj+1
    BARSYNC();
  }

  // butterfly reduce over the 8 cg lanes (lane bits 0-2; deterministic symmetric tree)
#pragma unroll
  for (int mskm = 1; mskm < 8; mskm <<= 1)
#pragma unroll
    for (int i = 0; i < NDISP; ++i)
#pragma unroll
      for (int ws = 0; ws < 4; ++ws)
        acc[i][ws] += __shfl_xor(acc[i][ws], mskm, 64);

  if (cg == 0) {
    float o[4];
#pragma unroll
    for (int ws = 0; ws < 4; ++ws) {
      float v1 = -1e30f, v2 = -1e30f, v3 = -1e30f;
      int   j1 = 0, j2 = 0, j3 = 0;
#pragma unroll
      for (int i = 0; i < NDISP; ++i) {
        float v = acc[i][ws] * 0.00390625f;    // mean: exact *2^-8
        if (v > v1)      { v3 = v2; j3 = j2; v2 = v1; j2 = j1; v1 = v; j1 = i; }
        else if (v > v2) { v3 = v2; j3 = j2; v2 = v;  j2 = i; }
        else if (v > v3) { v3 = v;  j3 = i; }
      }
      float e2 = expf(v2 - v1), e3 = expf(v3 - v1);
      float ssum = 1.0f + e2 + e3;
      o[ws] = ((float)j1 + e2 * (float)j2 + e3 * (float)j3) / ssum;
    }
    *reinterpret_cast<float4*>(&disp[(size_t)row * NW + w0]) = float4{o[0], o[1], o[2], o[3]};
  }
}

// ---------------- K2: convex upsample, one thread per (b,h,fy,w) -> 8 fx outputs ----------------
__global__ __launch_bounds__(256) void upsample_kernel(
    const float* __restrict__ disp, const float* __restrict__ mask,
    const int* __restrict__ itp, float* __restrict__ out)
{
  int idx = blockIdx.x * 256 + threadIdx.x;    // 8*80*8*160 = 819,200 exactly
  const int w  = idx % NW;
  const int fy = (idx / NW) & 7;
  const int h  = (idx / (NW * FAC)) % NH;
  const int b  = idx / (NW * FAC * NH);

  const float iters = (float)itp[0];
  const float temp  = 1.0f + __expf(-(iters - 1.0f));
  const float sc    = 1.44269504088896340736f / temp;  // log2(e)/temp

  const size_t hw = (size_t)NH * NW;
  const float* drow = disp + (size_t)b * hw;
  float d[9];
#pragma unroll
  for (int dy = 0; dy < 3; ++dy)
#pragma unroll
    for (int dx = 0; dx < 3; ++dx) {
      int h2 = h + dy - 1, w2 = w + dx - 1;
      bool ok = (h2 >= 0) && (h2 < NH) && (w2 >= 0) && (w2 < NW);
      d[dy * 3 + dx] = ok ? drow[h2 * NW + w2] : 0.f;
    }

  const float* mb = mask + (size_t)b * 576 * hw + (size_t)h * NW + w;
  float m[9][FAC];
#pragma unroll
  for (int j = 0; j < 9; ++j)
#pragma unroll
    for (int fx = 0; fx < FAC; ++fx)
      m[j][fx] = __builtin_nontemporal_load(mb + (size_t)((j * 8 + fy) * 8 + fx) * hw);

  float o[FAC];
#pragma unroll
  for (int fx = 0; fx < FAC; ++fx) {
    float mx = m[0][fx];
#pragma unroll
    for (int j = 1; j < 9; ++j) mx = fmaxf(mx, m[j][fx]);
    float ssum = 0.f, accv = 0.f;
#pragma unroll
    for (int j = 0; j < 9; ++j) {
      float e = exp2f((m[j][fx] - mx) * sc);
      ssum += e;
      accv += e * d[j];
    }
    o[fx] = (-8.0f * accv) * __builtin_amdgcn_rcpf(ssum);
  }

  float* op = out + ((size_t)b * (NH * FAC) + (size_t)(h * FAC + fy)) * (NW * FAC) + (size_t)w * FAC;
  f4v v0 = {o[0], o[1], o[2], o[3]};
  f4v v1 = {o[4], o[5], o[6], o[7]};
  __builtin_nontemporal_store(v0, reinterpret_cast<f4v*>(op));
  __builtin_nontemporal_store(v1, reinterpret_cast<f4v*>(op + 4));
}

extern "C" void kernel_launch(void* const* d_in, const int* in_sizes, int n_in,
                              void* d_out, int out_size, void* d_ws, size_t ws_size,
                              hipStream_t stream) {
  (void)in_sizes; (void)n_in; (void)out_size; (void)ws_size;
  const float* left  = (const float*)d_in[0];
  const float* right = (const float*)d_in[1];
  const float* mask  = (const float*)d_in[2];
  const int*   iters = (const int*)d_in[3];
  float* out  = (float*)d_out;
  float* disp = (float*)d_ws;   // 8*80*160 f32 scratch

  hipLaunchKernelGGL(cost_topk_kernel, dim3(NBATCH * NH), dim3(TPB1), 0, stream,
                     left, right, disp);
  hipLaunchKernelGGL(upsample_kernel, dim3(NBATCH * NH * FAC * NW / 256), dim3(256), 0, stream,
                     disp, mask, iters, out);
}

// Round 15
// 129.739 us; speedup vs baseline: 1.1517x; 1.1517x over previous
//
#include <hip/hip_runtime.h>
#include <cmath>

#define NBATCH 8
#define NCH    256
#define NH     80
#define NW     160
#define NDISP  24
#define FAC    8

constexpr int TPB1  = 128;                     // 2 waves per block (one tile: half 0 + half 1)
constexpr int WPB   = 2;
constexpr int NTILE = 5;                       // 32-wide w tiles per row
constexpr int SLOTS = 192;                     // per buffer: 128 R-quads + 64 L-quads (float4)
constexpr int NBUF  = 2;                       // depth-2 rotation -> vmcnt(3) steady state
constexpr int NSTEP = 16;                      // channels per wave (half of 32)

typedef __attribute__((address_space(1))) unsigned int gu32;
typedef __attribute__((address_space(3))) unsigned int lu32;

// aux=2 = NT: stream L/R straight from HBM, don't allocate L2/L3 (read-once data).
#define LDS_AUX 2

__device__ __forceinline__ void gload_lds16(const float* g, float4* l) {
  __builtin_amdgcn_global_load_lds((gu32*)g, (lu32*)l, 16, 0, LDS_AUX);
}

template <int N>
__device__ __forceinline__ void wait_vm() {
  if constexpr (N == 3)      asm volatile("s_waitcnt vmcnt(3)" ::: "memory");
  else                       asm volatile("s_waitcnt vmcnt(0)" ::: "memory");
  __builtin_amdgcn_sched_barrier(0);           // rule #18: pin consumers behind the wait
}

__device__ __forceinline__ void wait_lgkm0() {
  asm volatile("s_waitcnt lgkmcnt(0)" ::: "memory");
  __builtin_amdgcn_sched_barrier(0);
}

__device__ __forceinline__ float f4c(const float4& v, int k) {
  switch (k) { case 0: return v.x; case 1: return v.y; case 2: return v.z; default: return v.w; }
}

// ---------------- K1: cost volume + top3 + softmax expectation, channel-split 2-way ----------------
// block = one (row, tile); wave = half (16 channels); lanes = 8wq x 8cg.
// Depth-2 LDS pipeline per wave, NO barriers in the main loop; halves combined once at the end.
__global__ __launch_bounds__(TPB1) void cost_topk_kernel(
    const float* __restrict__ left, const float* __restrict__ right,
    float* __restrict__ disp)
{
  __shared__ float4 lds4[WPB][NBUF][SLOTS];    // 12 KB/block, wave-private [widx]

  const int lane = threadIdx.x & 63;
  const int widx = threadIdx.x >> 6;           // half 0/1
  const int tileid = blockIdx.x;               // 0..3199
  const int tile = tileid % NTILE;
  const int row  = tileid / NTILE;             // b*NH + h
  const int b    = row / NH;
  const int h    = row % NH;
  const int wb   = tile * 32;
  const int chb  = widx * NSTEP;               // channel base of this half

  const int cg = lane & 7;
  const int wq = lane >> 3;

  const size_t hw = (size_t)NH * NW;
  const float* lrow = left  + (size_t)b * NCH * hw + (size_t)h * NW;
  const float* rrow = right + (size_t)b * NCH * hw + (size_t)h * NW;

  // staging sources (per lane, this half's channel 0); slot s = c*16 + (q^c) [R], 128 + c*8 + (wq^c) [L]
  const int c0 = lane >> 4,        q0 = (lane & 15) ^ c0;        // R slots 0..63   (LDS ch 0..3)
  const int c1 = 4 + (lane >> 4),  q1 = (lane & 15) ^ c1;        // R slots 64..127 (LDS ch 4..7)
  const int cl = lane >> 3,        wqs = (lane & 7) ^ cl;        // L slots 128..191

  int off0 = wb - 32 + 4 * q0; if (off0 < 0) off0 = 0;           // clamp (overwritten by apron-zero)
  int off1 = wb - 32 + 4 * q1; if (off1 < 0) off1 = 0;

  const float* srcR0 = rrow + (size_t)(c0 * 32 + chb) * hw + off0;
  const float* srcR1 = rrow + (size_t)(c1 * 32 + chb) * hw + off1;
  const float* srcL  = lrow + (size_t)(cl * 32 + chb) * hw + wb + 4 * wqs;

  float4* const wbase = &lds4[widx][0][0];

#define STAGE(BP) do {                               \
    gload_lds16(srcR0, (BP));                        \
    gload_lds16(srcR1, (BP) + 64);                   \
    gload_lds16(srcL,  (BP) + 128);                  \
    srcR0 += hw; srcR1 += hw; srcL += hw; } while (0)

  // compute-side swizzled slots (per-thread constants)
  int rsl[7];
#pragma unroll
  for (int k = 0; k < 7; ++k) rsl[k] = cg * 16 + ((wq + 2 + k) ^ cg);
  const int lslot = 128 + cg * 8 + (wq ^ cg);

  float acc[NDISP][4];
#pragma unroll
  for (int i = 0; i < NDISP; ++i)
#pragma unroll
    for (int ws = 0; ws < 4; ++ws) acc[i][ws] = 0.f;

  auto fmastep = [&](const float4* base) {
    float4 Lq = base[lslot];
    float4 Qa = base[rsl[0]];
#pragma unroll
    for (int g = 0; g < 6; ++g) {
      float4 Qb = base[rsl[g + 1]];
      const int i0 = 20 - 4 * g;
#pragma unroll
      for (int di = 0; di < 4; ++di)
#pragma unroll
        for (int ws = 0; ws < 4; ++ws) {
          const int pos = ws - di + 4;               // 1..7 in [Qa|Qb]
          float rv = (pos < 4) ? f4c(Qa, pos) : f4c(Qb, pos - 4);
          acc[i0 + di][ws] = __builtin_fmaf(f4c(Lq, ws), rv, acc[i0 + di][ws]);
        }
      Qa = Qb;
    }
  };

  const float4 fzero{0.f, 0.f, 0.f, 0.f};
  const int azslot = (lane >> 3) * 16 + (lane & 7); // zeroes R q=0..7 per c (w<0 apron)

  // prologue: this half's channel 0 into buffer 0
  STAGE(wbase + 0 * SLOTS);

  // steady state: at step j, stage ch j+1 into buf (j+1)&1 BEFORE consuming buf j&1
#pragma unroll 2
  for (int j = 0; j < NSTEP; ++j) {
    wait_lgkm0();                                // WAR guard: step j-1's ds_reads retired
    if (j + 1 < NSTEP) {
      STAGE(wbase + ((j + 1) & 1) * SLOTS);
      wait_vm<3>();                              // ch j's 3 loads retired (6 - 3)
    } else {
      wait_vm<0>();
    }
    float4* bc = wbase + (j & 1) * SLOTS;
    if (tile == 0) bc[azslot] = fzero;
    fmastep(bc);
  }
#undef STAGE

  // butterfly reduce over the 8 cg lanes (deterministic symmetric tree; all lanes end with total)
#pragma unroll
  for (int mskm = 1; mskm < 8; mskm <<= 1)
#pragma unroll
    for (int i = 0; i < NDISP; ++i)
#pragma unroll
      for (int ws = 0; ws < 4; ++ws)
        acc[i][ws] += __shfl_xor(acc[i][ws], mskm, 64);

  // combine halves: wave 1 parks its sums in its (now dead) staging LDS, wave 0 adds
  if (widx == 1 && cg == 0) {
    float4* red = &lds4[1][0][0];
#pragma unroll
    for (int i = 0; i < NDISP; ++i)
      red[wq * NDISP + i] = float4{acc[i][0], acc[i][1], acc[i][2], acc[i][3]};
  }
  __syncthreads();

  if (widx == 0 && cg == 0) {
    const float4* red = &lds4[1][0][0];
    float o[4];
#pragma unroll
    for (int i = 0; i < NDISP; ++i) {
      float4 r = red[wq * NDISP + i];
      acc[i][0] += r.x; acc[i][1] += r.y; acc[i][2] += r.z; acc[i][3] += r.w;
    }
#pragma unroll
    for (int ws = 0; ws < 4; ++ws) {
      float v1 = -1e30f, v2 = -1e30f, v3 = -1e30f;
      int   j1 = 0, j2 = 0, j3 = 0;
#pragma unroll
      for (int i = 0; i < NDISP; ++i) {
        float v = acc[i][ws] * 0.00390625f;      // mean: exact *2^-8
        if (v > v1)      { v3 = v2; j3 = j2; v2 = v1; j2 = j1; v1 = v; j1 = i; }
        else if (v > v2) { v3 = v2; j3 = j2; v2 = v;  j2 = i; }
        else if (v > v3) { v3 = v;  j3 = i; }
      }
      float e2 = expf(v2 - v1), e3 = expf(v3 - v1);
      float ssum = 1.0f + e2 + e3;
      o[ws] = ((float)j1 + e2 * (float)j2 + e3 * (float)j3) / ssum;
    }
    *reinterpret_cast<float4*>(&disp[((size_t)b * NH + h) * NW + wb + wq * 4]) =
        float4{o[0], o[1], o[2], o[3]};
  }
}

// ---------------- K2: convex upsample, one thread per (b,h,fy,w) -> 8 fx outputs ----------------
__global__ __launch_bounds__(256) void upsample_kernel(
    const float* __restrict__ disp, const float* __restrict__ mask,
    const int* __restrict__ itp, float* __restrict__ out)
{
  int idx = blockIdx.x * 256 + threadIdx.x;    // 8*80*8*160 = 819,200 exactly
  const int w  = idx % NW;
  const int fy = (idx / NW) & 7;
  const int h  = (idx / (NW * FAC)) % NH;
  const int b  = idx / (NW * FAC * NH);

  const float iters = (float)itp[0];
  const float temp  = 1.0f + __expf(-(iters - 1.0f));
  const float sc    = 1.44269504088896340736f / temp;  // log2(e)/temp

  const size_t hw = (size_t)NH * NW;
  const float* drow = disp + (size_t)b * hw;
  float d[9];
#pragma unroll
  for (int dy = 0; dy < 3; ++dy)
#pragma unroll
    for (int dx = 0; dx < 3; ++dx) {
      int h2 = h + dy - 1, w2 = w + dx - 1;
      bool ok = (h2 >= 0) && (h2 < NH) && (w2 >= 0) && (w2 < NW);
      d[dy * 3 + dx] = ok ? drow[h2 * NW + w2] : 0.f;
    }

  const float* mb = mask + (size_t)b * 576 * hw + (size_t)h * NW + w;
  float m[9][FAC];
#pragma unroll
  for (int j = 0; j < 9; ++j)
#pragma unroll
    for (int fx = 0; fx < FAC; ++fx)
      m[j][fx] = mb[(size_t)((j * 8 + fy) * 8 + fx) * hw];

  float o[FAC];
#pragma unroll
  for (int fx = 0; fx < FAC; ++fx) {
    float mx = m[0][fx];
#pragma unroll
    for (int j = 1; j < 9; ++j) mx = fmaxf(mx, m[j][fx]);
    float ssum = 0.f, accv = 0.f;
#pragma unroll
    for (int j = 0; j < 9; ++j) {
      float e = exp2f((m[j][fx] - mx) * sc);
      ssum += e;
      accv += e * d[j];
    }
    o[fx] = (-8.0f * accv) * __builtin_amdgcn_rcpf(ssum);
  }

  float* op = out + ((size_t)b * (NH * FAC) + (size_t)(h * FAC + fy)) * (NW * FAC) + (size_t)w * FAC;
  *reinterpret_cast<float4*>(op)     = float4{o[0], o[1], o[2], o[3]};
  *reinterpret_cast<float4*>(op + 4) = float4{o[4], o[5], o[6], o[7]};
}

extern "C" void kernel_launch(void* const* d_in, const int* in_sizes, int n_in,
                              void* d_out, int out_size, void* d_ws, size_t ws_size,
                              hipStream_t stream) {
  (void)in_sizes; (void)n_in; (void)out_size; (void)ws_size;
  const float* left  = (const float*)d_in[0];
  const float* right = (const float*)d_in[1];
  const float* mask  = (const float*)d_in[2];
  const int*   iters = (const int*)d_in[3];
  float* out  = (float*)d_out;
  float* disp = (float*)d_ws;   // 8*80*160 f32 scratch

  hipLaunchKernelGGL(cost_topk_kernel, dim3(NBATCH * NH * NTILE), dim3(TPB1), 0, stream,
                     left, right, disp);
  hipLaunchKernelGGL(upsample_kernel, dim3(NBATCH * NH * FAC * NW / 256), dim3(256), 0, stream,
                     disp, mask, iters, out);
}

// Round 16
// 125.028 us; speedup vs baseline: 1.1951x; 1.0377x over previous
//
#include <hip/hip_runtime.h>
#include <cmath>

#define NBATCH 8
#define NCH    256
#define NH     80
#define NW     160
#define NDISP  24
#define FAC    8

constexpr int TPB1  = 128;                     // 2 waves per block (one tile: half 0 + half 1)
constexpr int WPB   = 2;
constexpr int NTILE = 5;                       // 32-wide w tiles per row
constexpr int SLOTS = 192;                     // per buffer: 128 R-quads + 64 L-quads (float4)
constexpr int NBUF  = 2;
constexpr int NSTEP = 16;                      // channels per wave (half of 32)

typedef float f4v __attribute__((ext_vector_type(4)));   // native vector (NT builtins require it)

__device__ __forceinline__ void wait_lgkm0() {
  asm volatile("s_waitcnt lgkmcnt(0)" ::: "memory");
  __builtin_amdgcn_sched_barrier(0);
}

__device__ __forceinline__ float f4c(const float4& v, int k) {
  switch (k) { case 0: return v.x; case 1: return v.y; case 2: return v.z; default: return v.w; }
}

// ---------------- K1: cost volume + top3 + softmax, channel-split 2-way, REG-STAGED ----------------
// R9 skeleton (wave = half-tile, 16 ch, no barriers) but staging goes global->VGPR->ds_write
// instead of the global_load_lds DMA path: 3 named f4v sets rotated over a 5x3 static-step loop
// (depth: load ch j+3 at step j, ds_write ch j+1, compute ch j). Compiler emits counted vmcnt
// at each ds_write via register deps — tests whether the LDS-DMA path was the supply binder.
__global__ __launch_bounds__(TPB1) void cost_topk_kernel(
    const float* __restrict__ left, const float* __restrict__ right,
    float* __restrict__ disp)
{
  __shared__ float4 lds4[WPB][NBUF][SLOTS];    // 12 KB/block, wave-private [widx]

  const int lane = threadIdx.x & 63;
  const int widx = threadIdx.x >> 6;           // half 0/1
  const int tileid = blockIdx.x;               // 0..3199
  const int tile = tileid % NTILE;
  const int row  = tileid / NTILE;             // b*NH + h
  const int b    = row / NH;
  const int h    = row % NH;
  const int wb   = tile * 32;
  const int chb  = widx * NSTEP;               // channel base of this half

  const int cg = lane & 7;
  const int wq = lane >> 3;

  const size_t hw = (size_t)NH * NW;
  const float* lrow = left  + (size_t)b * NCH * hw + (size_t)h * NW;
  const float* rrow = right + (size_t)b * NCH * hw + (size_t)h * NW;

  // staging sources (per lane); slot s = c*16 + (q^c) [R], 128 + c*8 + (wq^c) [L]; lane l owns
  // slots {l, 64+l, 128+l} -> invert the XOR on the source side.
  const int c0 = lane >> 4,        q0 = (lane & 15) ^ c0;        // R slots 0..63   (ch 0..3 of slab)
  const int c1 = 4 + (lane >> 4),  q1 = (lane & 15) ^ c1;        // R slots 64..127 (ch 4..7)
  const int cl = lane >> 3,        wqs = (lane & 7) ^ cl;        // L slots 128..191

  int off0 = wb - 32 + 4 * q0; if (off0 < 0) off0 = 0;           // clamp (overwritten by apron-zero)
  int off1 = wb - 32 + 4 * q1; if (off1 < 0) off1 = 0;

  const float* srcR0 = rrow + (size_t)(c0 * 32 + chb) * hw + off0;
  const float* srcR1 = rrow + (size_t)(c1 * 32 + chb) * hw + off1;
  const float* srcL  = lrow + (size_t)(cl * 32 + chb) * hw + wb + 4 * wqs;

  // three named register sets (static everywhere — rule #20)
  f4v S0r0, S0r1, S0l, S1r0, S1r1, S1l, S2r0, S2r1, S2l;

#define LOADS(S) do {                                                          \
    S##r0 = __builtin_nontemporal_load(reinterpret_cast<const f4v*>(srcR0));   \
    S##r1 = __builtin_nontemporal_load(reinterpret_cast<const f4v*>(srcR1));   \
    S##l  = __builtin_nontemporal_load(reinterpret_cast<const f4v*>(srcL));    \
    srcR0 += hw; srcR1 += hw; srcL += hw; } while (0)

#define WRITES(BP, S) do {                                                     \
    *reinterpret_cast<f4v*>(&(BP)[lane])       = S##r0;                        \
    *reinterpret_cast<f4v*>(&(BP)[64 + lane])  = S##r1;                        \
    *reinterpret_cast<f4v*>(&(BP)[128 + lane]) = S##l; } while (0)

  // compute-side swizzled slots (per-thread constants)
  int rsl[7];
#pragma unroll
  for (int k = 0; k < 7; ++k) rsl[k] = cg * 16 + ((wq + 2 + k) ^ cg);
  const int lslot = 128 + cg * 8 + (wq ^ cg);

  float acc[NDISP][4];
#pragma unroll
  for (int i = 0; i < NDISP; ++i)
#pragma unroll
    for (int ws = 0; ws < 4; ++ws) acc[i][ws] = 0.f;

  auto fmastep = [&](const float4* base) {
    float4 Lq = base[lslot];
    float4 Qa = base[rsl[0]];
#pragma unroll
    for (int g = 0; g < 6; ++g) {
      float4 Qb = base[rsl[g + 1]];
      const int i0 = 20 - 4 * g;
#pragma unroll
      for (int di = 0; di < 4; ++di)
#pragma unroll
        for (int ws = 0; ws < 4; ++ws) {
          const int pos = ws - di + 4;               // 1..7 in [Qa|Qb]
          float rv = (pos < 4) ? f4c(Qa, pos) : f4c(Qb, pos - 4);
          acc[i0 + di][ws] = __builtin_fmaf(f4c(Lq, ws), rv, acc[i0 + di][ws]);
        }
      Qa = Qb;
    }
  };

  const float4 fzero{0.f, 0.f, 0.f, 0.f};
  const int azslot = (lane >> 3) * 16 + (lane & 7); // zeroes R q=0..7 per c (w<0 apron)

  float4* p0 = &lds4[widx][0][0];              // buffer for even steps (swapped per outer iter)
  float4* p1 = &lds4[widx][1][0];

  // prologue: load ch 0,1,2 into S0,S1,S2; write ch0 -> p0 (counted vmcnt on S0 here)
  LOADS(S0); LOADS(S1); LOADS(S2);
  WRITES(p0, S0);

  // steady state: step j { lgkm WAR-guard; issue loads ch j+3; ds_write ch j+1; compute ch j }
  // 5 outer iters x 3 static steps + tail(step 15). Set roles per k: load S_k, write S_{(k+1)%3}.
#pragma unroll 1
  for (int it = 0; it < 5; ++it) {
    // k=0: j=3it — compute p0, write p1(ch j+1), load ch j+3 (always valid)
    wait_lgkm0();
    LOADS(S0);
    WRITES(p1, S1);
    __builtin_amdgcn_sched_barrier(0);
    if (tile == 0) p0[azslot] = fzero;
    fmastep(p0);
    // k=1: j=3it+1 — compute p1, write p0, load if it<4
    wait_lgkm0();
    if (it < 4) LOADS(S1);
    WRITES(p0, S2);
    __builtin_amdgcn_sched_barrier(0);
    if (tile == 0) p1[azslot] = fzero;
    fmastep(p1);
    // k=2: j=3it+2 — compute p0, write p1, load if it<4
    wait_lgkm0();
    if (it < 4) LOADS(S2);
    WRITES(p1, S0);
    __builtin_amdgcn_sched_barrier(0);
    if (tile == 0) p0[azslot] = fzero;
    fmastep(p0);
    float4* t = p0; p0 = p1; p1 = t;           // 3 steps flip parity
  }
  // tail: step 15 — ch15 was written at step 14; just compute
  wait_lgkm0();
  if (tile == 0) p0[azslot] = fzero;
  fmastep(p0);
#undef WRITES
#undef LOADS

  // butterfly reduce over the 8 cg lanes (deterministic symmetric tree; all lanes end with total)
#pragma unroll
  for (int mskm = 1; mskm < 8; mskm <<= 1)
#pragma unroll
    for (int i = 0; i < NDISP; ++i)
#pragma unroll
      for (int ws = 0; ws < 4; ++ws)
        acc[i][ws] += __shfl_xor(acc[i][ws], mskm, 64);

  // combine halves: wave 1 parks its sums in its (now dead) staging LDS, wave 0 adds
  if (widx == 1 && cg == 0) {
    float4* red = &lds4[1][0][0];
#pragma unroll
    for (int i = 0; i < NDISP; ++i)
      red[wq * NDISP + i] = float4{acc[i][0], acc[i][1], acc[i][2], acc[i][3]};
  }
  __syncthreads();

  if (widx == 0 && cg == 0) {
    const float4* red = &lds4[1][0][0];
    float o[4];
#pragma unroll
    for (int i = 0; i < NDISP; ++i) {
      float4 r = red[wq * NDISP + i];
      acc[i][0] += r.x; acc[i][1] += r.y; acc[i][2] += r.z; acc[i][3] += r.w;
    }
#pragma unroll
    for (int ws = 0; ws < 4; ++ws) {
      float v1 = -1e30f, v2 = -1e30f, v3 = -1e30f;
      int   j1 = 0, j2 = 0, j3 = 0;
#pragma unroll
      for (int i = 0; i < NDISP; ++i) {
        float v = acc[i][ws] * 0.00390625f;      // mean: exact *2^-8
        if (v > v1)      { v3 = v2; j3 = j2; v2 = v1; j2 = j1; v1 = v; j1 = i; }
        else if (v > v2) { v3 = v2; j3 = j2; v2 = v;  j2 = i; }
        else if (v > v3) { v3 = v;  j3 = i; }
      }
      float e2 = expf(v2 - v1), e3 = expf(v3 - v1);
      float ssum = 1.0f + e2 + e3;
      o[ws] = ((float)j1 + e2 * (float)j2 + e3 * (float)j3) / ssum;
    }
    *reinterpret_cast<float4*>(&disp[((size_t)b * NH + h) * NW + wb + wq * 4]) =
        float4{o[0], o[1], o[2], o[3]};
  }
}

// ---------------- K2: convex upsample, one thread per (b,h,fy,w) -> 8 fx outputs ----------------
__global__ __launch_bounds__(256) void upsample_kernel(
    const float* __restrict__ disp, const float* __restrict__ mask,
    const int* __restrict__ itp, float* __restrict__ out)
{
  int idx = blockIdx.x * 256 + threadIdx.x;    // 8*80*8*160 = 819,200 exactly
  const int w  = idx % NW;
  const int fy = (idx / NW) & 7;
  const int h  = (idx / (NW * FAC)) % NH;
  const int b  = idx / (NW * FAC * NH);

  const float iters = (float)itp[0];
  const float temp  = 1.0f + __expf(-(iters - 1.0f));
  const float sc    = 1.44269504088896340736f / temp;  // log2(e)/temp

  const size_t hw = (size_t)NH * NW;
  const float* drow = disp + (size_t)b * hw;
  float d[9];
#pragma unroll
  for (int dy = 0; dy < 3; ++dy)
#pragma unroll
    for (int dx = 0; dx < 3; ++dx) {
      int h2 = h + dy - 1, w2 = w + dx - 1;
      bool ok = (h2 >= 0) && (h2 < NH) && (w2 >= 0) && (w2 < NW);
      d[dy * 3 + dx] = ok ? drow[h2 * NW + w2] : 0.f;
    }

  const float* mb = mask + (size_t)b * 576 * hw + (size_t)h * NW + w;
  float m[9][FAC];
#pragma unroll
  for (int j = 0; j < 9; ++j)
#pragma unroll
    for (int fx = 0; fx < FAC; ++fx)
      m[j][fx] = mb[(size_t)((j * 8 + fy) * 8 + fx) * hw];

  float o[FAC];
#pragma unroll
  for (int fx = 0; fx < FAC; ++fx) {
    float mx = m[0][fx];
#pragma unroll
    for (int j = 1; j < 9; ++j) mx = fmaxf(mx, m[j][fx]);
    float ssum = 0.f, accv = 0.f;
#pragma unroll
    for (int j = 0; j < 9; ++j) {
      float e = exp2f((m[j][fx] - mx) * sc);
      ssum += e;
      accv += e * d[j];
    }
    o[fx] = (-8.0f * accv) * __builtin_amdgcn_rcpf(ssum);
  }

  float* op = out + ((size_t)b * (NH * FAC) + (size_t)(h * FAC + fy)) * (NW * FAC) + (size_t)w * FAC;
  *reinterpret_cast<float4*>(op)     = float4{o[0], o[1], o[2], o[3]};
  *reinterpret_cast<float4*>(op + 4) = float4{o[4], o[5], o[6], o[7]};
}

extern "C" void kernel_launch(void* const* d_in, const int* in_sizes, int n_in,
                              void* d_out, int out_size, void* d_ws, size_t ws_size,
                              hipStream_t stream) {
  (void)in_sizes; (void)n_in; (void)out_size; (void)ws_size;
  const float* left  = (const float*)d_in[0];
  const float* right = (const float*)d_in[1];
  const float* mask  = (const float*)d_in[2];
  const int*   iters = (const int*)d_in[3];
  float* out  = (float*)d_out;
  float* disp = (float*)d_ws;   // 8*80*160 f32 scratch

  hipLaunchKernelGGL(cost_topk_kernel, dim3(NBATCH * NH * NTILE), dim3(TPB1), 0, stream,
                     left, right, disp);
  hipLaunchKernelGGL(upsample_kernel, dim3(NBATCH * NH * FAC * NW / 256), dim3(256), 0, stream,
                     disp, mask, iters, out);
}